// Round 4
// baseline (103.376 us; speedup 1.0000x reference)
//
#include <hip/hip_runtime.h>
#include <math.h>

#define MAXB 1024   // max segments staged in LDS
#define NBLK 2048   // 8 blocks/CU * 256 CU

// ---- fallback setup (B > 64): starts[B+1] prefix + inverse softmax denom ----
__global__ void esl_setup(const int* __restrict__ lengths, int B,
                          const float* __restrict__ gamma_p,
                          int* __restrict__ starts,
                          float* __restrict__ inv_ssum) {
    const int tid = threadIdx.x;
    if (tid == 0) {
        int acc = 0;
        starts[0] = 0;
        for (int b = 0; b < B; ++b) { acc += lengths[b]; starts[b + 1] = acc; }
    }
    const float g = gamma_p[0];
    for (int b = tid; b < B; b += blockDim.x) {
        const int L = lengths[b];
        if (L <= 0) { inv_ssum[b] = 0.f; continue; }
        const int dni = (L - 1) > 1 ? (L - 1) : 1;
        const float a = 2.f * g / (float)dni;
        float ss;
        if (fabsf(a) < 1e-20f) ss = (float)L * __expf(-2.f * g);
        else ss = __expf(-2.f * g) * (expm1f(a * (float)L) / expm1f(a));
        inv_ssum[b] = 1.f / ss;
    }
}

__device__ __forceinline__ float sumexp16(const float4 v0, const float4 v1,
                                          const float4 v2, const float4 v3) {
    return __expf(v0.x) + __expf(v0.y) + __expf(v0.z) + __expf(v0.w)
         + __expf(v1.x) + __expf(v1.y) + __expf(v1.z) + __expf(v1.w)
         + __expf(v2.x) + __expf(v2.y) + __expf(v2.z) + __expf(v2.w)
         + __expf(v3.x) + __expf(v3.y) + __expf(v3.z) + __expf(v3.w);
}

// ---- main: contiguous token chunk per wave, 2 tokens per iteration ----
__global__ __launch_bounds__(256)
void esl_main(const float* __restrict__ outputs,
              const int* __restrict__ targets,
              const int* __restrict__ lengths,
              const int* __restrict__ g_starts,
              const float* __restrict__ g_inv,
              const float* __restrict__ gamma_p,
              int T, int B, int C, int inblock,
              float* __restrict__ partials) {
    __shared__ int   sh_starts[MAXB + 1];
    __shared__ float sh_inv[MAXB];
    __shared__ float sh_part[4];

    const int tid = threadIdx.x;
    const float g = gamma_p[0];

    if (inblock) {
        // B <= 64: wave 0 builds starts + inv_ssum locally (shfl prefix scan)
        if (tid < 64) {
            const int b = tid;
            const int len = (b < B) ? lengths[b] : 0;
            int sc = len;
            #pragma unroll
            for (int off = 1; off < 64; off <<= 1) {
                const int u = __shfl_up(sc, off, 64);
                if (tid >= off) sc += u;
            }
            if (b < B) {
                sh_starts[b] = sc - len;
                if (b == B - 1) sh_starts[B] = sc;
                float inv = 0.f;
                const int L = len;
                if (L > 0) {
                    const int dni = (L - 1) > 1 ? (L - 1) : 1;
                    const float a = 2.f * g / (float)dni;
                    float ss;
                    if (fabsf(a) < 1e-20f) ss = (float)L * __expf(-2.f * g);
                    else ss = __expf(-2.f * g) * (expm1f(a * (float)L) / expm1f(a));
                    inv = 1.f / ss;
                }
                sh_inv[b] = inv;
            }
        }
    } else {
        const int nb = (B < MAXB) ? B : MAXB;
        for (int i = tid; i < nb + 1; i += blockDim.x) sh_starts[i] = g_starts[i];
        for (int i = tid; i < nb;     i += blockDim.x) sh_inv[i]   = g_inv[i];
    }
    __syncthreads();

    const int wid  = tid >> 6;
    const int lane = tid & 63;
    const int* stp    = (B <= MAXB) ? sh_starts : g_starts;
    const float* invp = (B <= MAXB) ? sh_inv    : g_inv;

    float acc = 0.f;

    if (C == 1024) {
        // contiguous chunk of tokens per wave -> segment state is monotone
        const int nwaves = gridDim.x * 4;
        const int w = blockIdx.x * 4 + wid;
        const int npw = (T + nwaves - 1) / nwaves;
        const int tbeg = w * npw;
        const int tend = (tbeg + npw < T) ? tbeg + npw : T;

        if (tbeg < T) {
            // one binary search per wave
            int lo = 0, hi = B - 1;
            while (lo < hi) {
                const int mid = (lo + hi + 1) >> 1;
                if (stp[mid] <= tbeg) lo = mid; else hi = mid - 1;
            }
            int seg = lo;
            int st  = stp[seg];
            int en  = stp[seg + 1];
            float slope = 0.f, winv = 0.f;
            {
                const float dnl = fmaxf((float)(en - st) - 1.f, 1.f);
                slope = __fdividef(2.f * g, dnl);
                winv  = invp[seg];
            }
            const float n2g = -2.f * g;

            // advance segment state so that token tt is inside [st, en)
            #define ESL_ADV(tt)                                                    \
                while ((tt) >= en) {                                               \
                    ++seg; st = en; en = stp[seg + 1];                             \
                    const float dnl_ = fmaxf((float)(en - st) - 1.f, 1.f);         \
                    slope = __fdividef(2.f * g, dnl_);                             \
                    winv  = invp[seg];                                             \
                }

            int t = tbeg;
            for (; t + 1 < tend; t += 2) {
                const float* rowA = outputs + (size_t)t * 1024;
                const float* rowB = rowA + 1024;
                const float4* ra = (const float4*)rowA;
                const float4* rb = (const float4*)rowB;
                const float4 a0 = ra[lane], a1 = ra[lane + 64],
                             a2 = ra[lane + 128], a3 = ra[lane + 192];
                const float4 b0 = rb[lane], b1 = rb[lane + 64],
                             b2 = rb[lane + 128], b3 = rb[lane + 192];
                const float xa = rowA[targets[t]];
                const float xb = rowB[targets[t + 1]];

                float sa = sumexp16(a0, a1, a2, a3);
                float sb = sumexp16(b0, b1, b2, b3);
                #pragma unroll
                for (int off = 32; off; off >>= 1) {
                    sa += __shfl_xor(sa, off, 64);
                    sb += __shfl_xor(sb, off, 64);
                }
                const float lseA = __logf(sa);
                const float lseB = __logf(sb);

                ESL_ADV(t);
                const float wA = __expf(fmaf((float)(t - st), slope, n2g)) * winv;
                ESL_ADV(t + 1);
                const float wB = __expf(fmaf((float)(t + 1 - st), slope, n2g)) * winv;

                acc += (lseA - xa) * wA + (lseB - xb) * wB;
            }
            if (t < tend) {  // odd remainder
                const float* rowA = outputs + (size_t)t * 1024;
                const float4* ra = (const float4*)rowA;
                const float4 a0 = ra[lane], a1 = ra[lane + 64],
                             a2 = ra[lane + 128], a3 = ra[lane + 192];
                const float xa = rowA[targets[t]];
                float sa = sumexp16(a0, a1, a2, a3);
                #pragma unroll
                for (int off = 32; off; off >>= 1) sa += __shfl_xor(sa, off, 64);
                const float lseA = __logf(sa);
                ESL_ADV(t);
                const float wA = __expf(fmaf((float)(t - st), slope, n2g)) * winv;
                acc += (lseA - xa) * wA;
            }
            #undef ESL_ADV
        }
    } else {
        // generic path (max-subtracted, per-token binary search), grid-stride
        const int stride = gridDim.x * 4;
        for (int t = blockIdx.x * 4 + wid; t < T; t += stride) {
            const float* rowp = outputs + (size_t)t * (size_t)C;
            const float xt = rowp[targets[t]];
            float m = -3.402823e38f, s = 0.f;
            for (int j = lane; j < C; j += 64) m = fmaxf(m, rowp[j]);
            #pragma unroll
            for (int off = 32; off; off >>= 1) m = fmaxf(m, __shfl_xor(m, off, 64));
            for (int j = lane; j < C; j += 64) s += __expf(rowp[j] - m);
            #pragma unroll
            for (int off = 32; off; off >>= 1) s += __shfl_xor(s, off, 64);
            const float lse = m + __logf(s);
            int lo = 0, hi = B - 1;
            while (lo < hi) {
                const int mid = (lo + hi + 1) >> 1;
                if (stp[mid] <= t) lo = mid; else hi = mid - 1;
            }
            const int st  = stp[lo];
            const int L   = stp[lo + 1] - st;
            const int pos = t - st;
            const float dn  = (float)((L - 1) > 1 ? (L - 1) : 1);
            const float raw = -g + (2.f * g) * ((float)pos / dn);
            acc += (lse - xt) * __expf(raw - g) * invp[lo];
        }
    }

    if (lane == 0) sh_part[wid] = acc;
    __syncthreads();
    if (tid == 0)
        partials[blockIdx.x] = sh_part[0] + sh_part[1] + sh_part[2] + sh_part[3];
}

// ---- finish: reduce partials, divide by B ----
__global__ __launch_bounds__(256)
void esl_finish(const float* __restrict__ partials, int n, int B,
                float* __restrict__ out) {
    __shared__ float sh[4];
    float s = 0.f;
    for (int i = threadIdx.x; i < n; i += blockDim.x) s += partials[i];
    #pragma unroll
    for (int off = 32; off; off >>= 1) s += __shfl_xor(s, off, 64);
    const int wid = threadIdx.x >> 6;
    if ((threadIdx.x & 63) == 0) sh[wid] = s;
    __syncthreads();
    if (threadIdx.x == 0) out[0] = (sh[0] + sh[1] + sh[2] + sh[3]) / (float)B;
}

extern "C" void kernel_launch(void* const* d_in, const int* in_sizes, int n_in,
                              void* d_out, int out_size, void* d_ws, size_t ws_size,
                              hipStream_t stream) {
    const float* outputs = (const float*)d_in[0];
    const int*   targets = (const int*)d_in[1];
    const int*   lengths = (const int*)d_in[2];
    const float* gamma   = (const float*)d_in[3];
    float* out = (float*)d_out;

    const int T = in_sizes[1];
    const int B = in_sizes[2];
    const int C = (int)(in_sizes[0] / T);

    int*   starts   = (int*)d_ws;
    float* inv_ssum = (float*)((char*)d_ws + sizeof(int) * (size_t)(B + 1));
    float* partials = inv_ssum + B;

    const int inblock = (B <= 64) ? 1 : 0;
    if (!inblock)
        esl_setup<<<1, 256, 0, stream>>>(lengths, B, gamma, starts, inv_ssum);

    int grid = NBLK;
    const int max_needed = (T + 3) / 4;
    if (grid > max_needed) grid = max_needed;
    esl_main<<<grid, 256, 0, stream>>>(outputs, targets, lengths, starts, inv_ssum,
                                       gamma, T, B, C, inblock, partials);
    esl_finish<<<1, 256, 0, stream>>>(partials, grid, B, out);
}